// Round 2
// baseline (510.104 us; speedup 1.0000x reference)
//
#include <hip/hip_runtime.h>
#include <cstdint>

#define DEVI __device__ __forceinline__

typedef __bf16 bf16x8_t __attribute__((ext_vector_type(8)));
typedef float f32x4_t __attribute__((ext_vector_type(4)));

typedef const __attribute__((address_space(1))) unsigned int* gas_t;
typedef __attribute__((address_space(3))) unsigned int* las_t;

// async global->LDS, 16B per lane, dst = wave-uniform base (+lane*16 by HW)
DEVI void glds16(const void* g, void* l) {
  __builtin_amdgcn_global_load_lds((gas_t)g, (las_t)l, 16, 0, 0);
}

DEVI uint16_t f2b(float f) {  // fp32 -> bf16 RNE
  uint32_t u = __builtin_bit_cast(uint32_t, f);
  u += 0x7fffu + ((u >> 16) & 1u);
  return (uint16_t)(u >> 16);
}

// meta: [0..7] counts, [8..16] offsets(9), [17..24] fill, [26] nT256,
// [32+t] tileExpert, [80+t] tilePos0, [128+t] tileValidEnd   (t < 40)
static constexpr int MAXT = 40;

// ---------------- gate: logits + top2 + softmax ----------------
__global__ __launch_bounds__(256) void moe_gate(const float* __restrict__ x,
    const float* __restrict__ Wg, const float* __restrict__ bg,
    int* __restrict__ gidx, float* __restrict__ gw) {
  const int lane = threadIdx.x & 63;
  const int b = blockIdx.x * 4 + (threadIdx.x >> 6);
  float acc[8];
#pragma unroll
  for (int e = 0; e < 8; ++e) acc[e] = 0.f;
  const float* xr = x + (size_t)b * 1024;
#pragma unroll
  for (int it = 0; it < 4; ++it) {
    const int d0 = it * 256 + lane * 4;
    float4 xv = *(const float4*)(xr + d0);
    float xs[4] = {xv.x, xv.y, xv.z, xv.w};
#pragma unroll
    for (int q = 0; q < 4; ++q) {
      const float4* wrow = (const float4*)(Wg + (size_t)(d0 + q) * 8);
      float4 wa = wrow[0], wb = wrow[1];
      acc[0] += xs[q] * wa.x; acc[1] += xs[q] * wa.y;
      acc[2] += xs[q] * wa.z; acc[3] += xs[q] * wa.w;
      acc[4] += xs[q] * wb.x; acc[5] += xs[q] * wb.y;
      acc[6] += xs[q] * wb.z; acc[7] += xs[q] * wb.w;
    }
  }
#pragma unroll
  for (int off = 32; off; off >>= 1)
#pragma unroll
    for (int e = 0; e < 8; ++e) acc[e] += __shfl_xor(acc[e], off, 64);
  if (lane == 0) {
    float l[8];
#pragma unroll
    for (int e = 0; e < 8; ++e) l[e] = acc[e] + bg[e];
    int i0 = 0;
#pragma unroll
    for (int e = 1; e < 8; ++e) if (l[e] > l[i0]) i0 = e;   // strict > : matches top_k tie rule
    int i1 = (i0 == 0) ? 1 : 0;
#pragma unroll
    for (int e = 0; e < 8; ++e) if (e != i0 && l[e] > l[i1]) i1 = e;
    float ex = expf(l[i1] - l[i0]);
    float s = 1.f + ex;
    gidx[2 * b] = i0; gidx[2 * b + 1] = i1;
    gw[2 * b] = 1.f / s; gw[2 * b + 1] = ex / s;
  }
}

// ---------------- scan: counts -> offsets -> 256-row tile table ----------------
__global__ __launch_bounds__(256) void moe_scan(const int* __restrict__ gidx,
                                                int* __restrict__ meta) {
  __shared__ int cnt[8];
  if (threadIdx.x < 8) cnt[threadIdx.x] = 0;
  __syncthreads();
  int loc[8] = {0, 0, 0, 0, 0, 0, 0, 0};
  for (int i = threadIdx.x; i < 8192; i += 256) {
    int e = gidx[i];
#pragma unroll
    for (int q = 0; q < 8; ++q) loc[q] += (e == q) ? 1 : 0;
  }
#pragma unroll
  for (int q = 0; q < 8; ++q) atomicAdd(&cnt[q], loc[q]);
  __syncthreads();
  if (threadIdx.x == 0) {
    int off = 0, t = 0;
    for (int e = 0; e < 8; ++e) {
      int c = cnt[e];
      meta[e] = c;
      meta[8 + e] = off;
      meta[17 + e] = 0;  // fill counters
      int nt = (c + 255) >> 8;
      for (int mt = 0; mt < nt; ++mt) {
        meta[32 + t] = e;
        meta[80 + t] = off + mt * 256;
        meta[128 + t] = off + c;
        ++t;
      }
      off += c;
    }
    meta[16] = off;
    meta[26] = t;
  }
}

// ---------------- scatter assignments into expert-sorted lists ----------------
__global__ __launch_bounds__(256) void moe_scatter(const int* __restrict__ gidx,
    const float* __restrict__ gw, int* __restrict__ meta,
    int* __restrict__ row_index, float* __restrict__ row_w) {
  int i = blockIdx.x * 256 + threadIdx.x;  // 8192 assignments
  int e = gidx[i];
  int pos = meta[8 + e] + atomicAdd(&meta[17 + e], 1);
  row_index[pos] = i >> 1;
  row_w[pos] = gw[i];
}

// ---------------- x fp32 -> bf16 ----------------
__global__ __launch_bounds__(256) void moe_cvtx(const float* __restrict__ x,
                                                uint16_t* __restrict__ xb) {
  size_t i = ((size_t)blockIdx.x * 256 + threadIdx.x) * 4;
  float4 v = *(const float4*)(x + i);
  uint64_t pk = (uint64_t)f2b(v.x) | ((uint64_t)f2b(v.y) << 16) |
                ((uint64_t)f2b(v.z) << 32) | ((uint64_t)f2b(v.w) << 48);
  *(uint64_t*)(xb + i) = pk;
}

// ---------------- W [E][K][N] fp32 -> Wt [E][N][K] bf16 ----------------
__global__ __launch_bounds__(256) void moe_transpose(const float* __restrict__ in,
                                                     uint16_t* __restrict__ outp,
                                                     int K, int N) {
  __shared__ uint16_t t[64][72];
  const int e = blockIdx.z;
  const int k0 = blockIdx.y * 64, n0 = blockIdx.x * 64;
  const int r = threadIdx.x >> 2;          // 0..63
  const int c0 = (threadIdx.x & 3) * 16;   // 0,16,32,48
  const float* src = in + ((size_t)e * K + k0 + r) * N + n0 + c0;
#pragma unroll
  for (int q = 0; q < 4; ++q) {
    float4 v = *(const float4*)(src + q * 4);
    uint64_t pk = (uint64_t)f2b(v.x) | ((uint64_t)f2b(v.y) << 16) |
                  ((uint64_t)f2b(v.z) << 32) | ((uint64_t)f2b(v.w) << 48);
    *(uint64_t*)&t[r][c0 + q * 4] = pk;
  }
  __syncthreads();
  alignas(16) uint16_t buf[16];
#pragma unroll
  for (int j = 0; j < 16; ++j) buf[j] = t[c0 + j][r];
  uint16_t* dst = outp + ((size_t)e * N + n0 + r) * K + k0 + c0;
  *(uint4*)dst = *(const uint4*)&buf[0];
  *(uint4*)(dst + 8) = *(const uint4*)&buf[8];
}

// ============ 256x256 8-phase GEMM, BK=64, 8 waves (2Mx4N), 128KiB LDS ======
// LDS regions: [buf(2)][A/B(2)][khalf(2)] of 256rows x 32k bf16 (16KiB each).
// Unit stream H = 4*kt + u, u: 0=(A,ks0) 1=(B,ks0) 2=(A,ks1) 3=(B,ks1).
// Iter i computes K-tiles 2i (phases 0-3) and 2i+1 (phases 4-7); phase p
// stages unit H=8i+6+p (lead 6). vmcnt(4) at phases 3,7 => K-tile complete
// before its group. Region-overwrite safety hand-verified: each stage lands
// strictly after the previous tenant's last-read barrier.
// MODE 1: h = relu(gather(xb) @ W1t^T + b1)     (ND=4096, KD=1024, KSL=1)
// MODE 2: out[rix] += rw * (h @ W2t^T + b2)     (ND=1024, KD=4096, KSL=2)
template <int KD, int ND, int MODE, int KSL>
__global__ __launch_bounds__(512, 2) void moe_gemm8(
    const uint16_t* __restrict__ Am, const uint16_t* __restrict__ Bt,
    const float* __restrict__ bias, const int* __restrict__ meta,
    const int* __restrict__ row_index, const float* __restrict__ row_w,
    uint16_t* __restrict__ hout, float* __restrict__ out) {
  constexpr int NB = ND / 256;
  constexpr int KSLEN = KD / KSL;
  constexpr int NKT = KSLEN / 64;
  constexpr int NIT = NKT / 2;
  extern __shared__ uint16_t lds[];

  // T1: bijective XCD swizzle on flat block id (nb innermost => same-tile
  // blocks share an XCD => A-panel L2 reuse)
  const int nwg = gridDim.x;
  const int orig = blockIdx.x;
  const int q = nwg >> 3, r8 = nwg & 7, xcd = orig & 7, loc = orig >> 3;
  int wg = (xcd < r8 ? xcd * (q + 1) : r8 * (q + 1) + (xcd - r8) * q) + loc;
  const int nb = wg % NB; wg /= NB;
  const int ks2 = wg % KSL; wg /= KSL;
  const int ty = wg;
  if (ty >= meta[26]) return;
  const int e = meta[32 + ty];
  const int pos0 = meta[80 + ty];
  const int vend = meta[128 + ty];
  const int k0 = ks2 * KSLEN;

  const int tid = threadIdx.x;
  const int lane = tid & 63;
  const int w = tid >> 6;
  const int wr = w >> 2, wc = w & 3;

  // staging: chunk c = l*512+tid; r=c>>2, ci=c&3, src k-chunk = ci^(r&3)
  const int crow = tid >> 2;
  const int swz = (tid & 3) ^ (crow & 3);
  uint32_t aoff[2], boff[2];
#pragma unroll
  for (int l = 0; l < 2; ++l) {
    int r = l * 128 + crow;
    int pos = pos0 + r; if (pos > 8191) pos = 8191;
    int arow = (MODE == 1) ? row_index[pos] : pos;
    aoff[l] = (uint32_t)arow * (KD * 2) + (uint32_t)(k0 * 2) + swz * 16;
    boff[l] = (uint32_t)(e * ND + nb * 256 + r) * (KD * 2) + (uint32_t)(k0 * 2) + swz * 16;
  }
  const char* Ag = (const char*)Am;
  const char* Bg = (const char*)Bt;

  const int dst0 = (w * 64) * 8;          // elems; HW adds lane*16B
  const int dst1 = (512 + w * 64) * 8;

  auto stageUnit = [&](int H) {
    int kt = H >> 2; if (kt > NKT - 1) kt = NKT - 1;  // tail clamp: rewrites identical bytes
    const int u = H & 3;                               // compile-time at all call sites
    const int ab = u & 1, ks = u >> 1;
    uint16_t* dst = lds + ((((kt & 1) * 2 + ab) * 2 + ks) << 13);
    uint32_t kadd = (uint32_t)kt * 128 + (uint32_t)ks * 64;
    if (ab == 0) {
      glds16(Ag + (aoff[0] + kadd), dst + dst0);
      glds16(Ag + (aoff[1] + kadd), dst + dst1);
    } else {
      glds16(Bg + (boff[0] + kadd), dst + dst0);
      glds16(Bg + (boff[1] + kadd), dst + dst1);
    }
  };

  // fragment read offsets (elems): row*32 + ((lane>>4)^(lane&3))*8
  const int fRow = (lane & 15) * 32;
  const int fSwz = ((lane >> 4) ^ (lane & 3)) * 8;
  const int aBaseR = (wr * 128) * 32;
  const int bBaseR = (wc * 64) * 32;

  f32x4_t acc[8][4];
  f32x4_t z; z[0] = 0.f; z[1] = 0.f; z[2] = 0.f; z[3] = 0.f;
#pragma unroll
  for (int m = 0; m < 8; ++m)
#pragma unroll
    for (int n = 0; n < 4; ++n) acc[m][n] = z;

  // prologue: units 0..5 (K-tile0 all, K-tile1 ks0), wait K-tile0
#pragma unroll
  for (int H = 0; H < 6; ++H) stageUnit(H);
  asm volatile("s_waitcnt vmcnt(4)" ::: "memory");
  __builtin_amdgcn_s_barrier();
  asm volatile("" ::: "memory");

  for (int i = 0; i < NIT; ++i) {
    bf16x8_t bfr[4];
#pragma unroll
    for (int p = 0; p < 8; ++p) {
      const int g = p >> 2, sub = p & 3, ksp = sub >> 1, mh = sub & 1;
      const uint16_t* Ar = lds + (((g * 2 + 0) * 2 + ksp) << 13);
      const uint16_t* Br = lds + (((g * 2 + 1) * 2 + ksp) << 13);
      bf16x8_t af[4];
#pragma unroll
      for (int m = 0; m < 4; ++m)
        af[m] = *(const bf16x8_t*)(Ar + aBaseR + (mh * 64 + m * 16) * 32 + fRow + fSwz);
      if (mh == 0) {
#pragma unroll
        for (int n = 0; n < 4; ++n)
          bfr[n] = *(const bf16x8_t*)(Br + bBaseR + n * 16 * 32 + fRow + fSwz);
      }
      stageUnit(8 * i + 6 + p);
      asm volatile("" ::: "memory");
      __builtin_amdgcn_s_barrier();
      asm volatile("s_waitcnt lgkmcnt(0)" ::: "memory");
      __builtin_amdgcn_s_setprio(1);
#pragma unroll
      for (int m = 0; m < 4; ++m)
#pragma unroll
        for (int n = 0; n < 4; ++n)
          acc[mh * 4 + m][n] = __builtin_amdgcn_mfma_f32_16x16x32_bf16(
              af[m], bfr[n], acc[mh * 4 + m][n], 0, 0, 0);
      __builtin_amdgcn_s_setprio(0);
      if (sub == 3) asm volatile("s_waitcnt vmcnt(4)" ::: "memory");
      __builtin_amdgcn_s_barrier();
      asm volatile("" ::: "memory");
    }
  }

  // epilogue: C/D mapping col=lane&15, row=(lane>>4)*4+i
  const int cbase = nb * 256 + wc * 64;
  if constexpr (MODE == 1) {
#pragma unroll
    for (int M = 0; M < 8; ++M) {
      int pr = pos0 + wr * 128 + M * 16 + ((lane >> 4) << 2);
#pragma unroll
      for (int i2 = 0; i2 < 4; ++i2) {
        int pos = pr + i2;
        if (pos < vend) {
#pragma unroll
          for (int n = 0; n < 4; ++n) {
            int col = cbase + n * 16 + (lane & 15);
            float v = acc[M][n][i2] + bias[e * ND + col];
            hout[(size_t)pos * ND + col] = f2b(fmaxf(v, 0.f));
          }
        }
      }
    }
  } else {
#pragma unroll
    for (int M = 0; M < 8; ++M) {
      int pr = pos0 + wr * 128 + M * 16 + ((lane >> 4) << 2);
#pragma unroll
      for (int i2 = 0; i2 < 4; ++i2) {
        int pos = pr + i2;
        if (pos < vend) {
          int bi = row_index[pos];
          float wgt = row_w[pos];
          float* orow = out + (size_t)bi * ND;
#pragma unroll
          for (int n = 0; n < 4; ++n) {
            int col = cbase + n * 16 + (lane & 15);
            float bterm = (ks2 == 0) ? bias[e * ND + col] : 0.f;
            atomicAdd(orow + col, (acc[M][n][i2] + bterm) * wgt);
          }
        }
      }
    }
  }
}

extern "C" void kernel_launch(void* const* d_in, const int* in_sizes, int n_in,
                              void* d_out, int out_size, void* d_ws, size_t ws_size,
                              hipStream_t stream) {
  const float* x  = (const float*)d_in[0];   // [4096,1024]
  const float* Wg = (const float*)d_in[1];   // [1024,8]
  const float* bg = (const float*)d_in[2];   // [8]
  const float* W1 = (const float*)d_in[3];   // [8,1024,4096]
  const float* b1 = (const float*)d_in[4];   // [8,4096]
  const float* W2 = (const float*)d_in[5];   // [8,4096,1024]
  const float* b2 = (const float*)d_in[6];   // [8,1024]
  float* out = (float*)d_out;                // [4096,1024]

  char* ws = (char*)d_ws;
  uint16_t* w1t = (uint16_t*)ws; ws += (size_t)8 * 4096 * 1024 * 2;  // [E][H][D] bf16
  uint16_t* w2t = (uint16_t*)ws; ws += (size_t)8 * 1024 * 4096 * 2;  // [E][O][H] bf16
  uint16_t* xb  = (uint16_t*)ws; ws += (size_t)4096 * 1024 * 2;      // [B][D] bf16
  uint16_t* h   = (uint16_t*)ws; ws += (size_t)8192 * 4096 * 2;      // [8192][H] bf16
  int*   gidx = (int*)ws;   ws += 8192 * 4;
  float* gw   = (float*)ws; ws += 8192 * 4;
  int*   rix  = (int*)ws;   ws += 8192 * 4;
  float* rw   = (float*)ws; ws += 8192 * 4;
  int*   meta = (int*)ws;   ws += 4096;

  static bool attr_done = false;
  if (!attr_done) {  // host-side config, not a stream op; idempotent
    hipFuncSetAttribute((const void*)moe_gemm8<1024, 4096, 1, 1>,
                        hipFuncAttributeMaxDynamicSharedMemorySize, 131072);
    hipFuncSetAttribute((const void*)moe_gemm8<4096, 1024, 2, 2>,
                        hipFuncAttributeMaxDynamicSharedMemorySize, 131072);
    attr_done = true;
  }

  hipMemsetAsync(d_out, 0, (size_t)4096 * 1024 * 4, stream);
  moe_cvtx<<<4096, 256, 0, stream>>>(x, xb);
  moe_transpose<<<dim3(4096 / 64, 1024 / 64, 8), 256, 0, stream>>>(W1, w1t, 1024, 4096);
  moe_transpose<<<dim3(1024 / 64, 4096 / 64, 8), 256, 0, stream>>>(W2, w2t, 4096, 1024);
  moe_gate<<<1024, 256, 0, stream>>>(x, Wg, bg, gidx, gw);
  moe_scan<<<1, 256, 0, stream>>>(gidx, meta);
  moe_scatter<<<32, 256, 0, stream>>>(gidx, gw, meta, rix, rw);
  moe_gemm8<1024, 4096, 1, 1><<<dim3(16 * MAXT), 512, 131072, stream>>>(
      xb, w1t, b1, meta, rix, rw, h, nullptr);
  moe_gemm8<4096, 1024, 2, 2><<<dim3(4 * 2 * MAXT), 512, 131072, stream>>>(
      h, w2t, b2, meta, rix, rw, nullptr, out);
}

// Round 3
// 431.695 us; speedup vs baseline: 1.1816x; 1.1816x over previous
//
#include <hip/hip_runtime.h>
#include <cstdint>

#define DEVI __device__ __forceinline__

typedef __bf16 bf16x8_t __attribute__((ext_vector_type(8)));
typedef float f32x4_t __attribute__((ext_vector_type(4)));

typedef const __attribute__((address_space(1))) unsigned int* gas_t;
typedef __attribute__((address_space(3))) unsigned int* las_t;

// async global->LDS, 16B per lane, dst = wave-uniform base (+lane*16 by HW)
DEVI void glds16(const void* g, void* l) {
  __builtin_amdgcn_global_load_lds((gas_t)g, (las_t)l, 16, 0, 0);
}

DEVI uint16_t f2b(float f) {  // fp32 -> bf16 RNE
  uint32_t u = __builtin_bit_cast(uint32_t, f);
  u += 0x7fffu + ((u >> 16) & 1u);
  return (uint16_t)(u >> 16);
}

// meta layout (ints): [0..7] counts, [8..16] offsets(9), [17..24] fill,
// [25] nTiles128, [32..103] tileExpert, [104..175] tilePos0, [176..247] tileValidEnd
static constexpr int MAXT = 72;

// ---------------- gate: logits + top2 + softmax ----------------
__global__ __launch_bounds__(256) void moe_gate(const float* __restrict__ x,
    const float* __restrict__ Wg, const float* __restrict__ bg,
    int* __restrict__ gidx, float* __restrict__ gw) {
  const int lane = threadIdx.x & 63;
  const int b = blockIdx.x * 4 + (threadIdx.x >> 6);
  float acc[8];
#pragma unroll
  for (int e = 0; e < 8; ++e) acc[e] = 0.f;
  const float* xr = x + (size_t)b * 1024;
#pragma unroll
  for (int it = 0; it < 4; ++it) {
    const int d0 = it * 256 + lane * 4;
    float4 xv = *(const float4*)(xr + d0);
    float xs[4] = {xv.x, xv.y, xv.z, xv.w};
#pragma unroll
    for (int q = 0; q < 4; ++q) {
      const float4* wrow = (const float4*)(Wg + (size_t)(d0 + q) * 8);
      float4 wa = wrow[0], wb = wrow[1];
      acc[0] += xs[q] * wa.x; acc[1] += xs[q] * wa.y;
      acc[2] += xs[q] * wa.z; acc[3] += xs[q] * wa.w;
      acc[4] += xs[q] * wb.x; acc[5] += xs[q] * wb.y;
      acc[6] += xs[q] * wb.z; acc[7] += xs[q] * wb.w;
    }
  }
#pragma unroll
  for (int off = 32; off; off >>= 1)
#pragma unroll
    for (int e = 0; e < 8; ++e) acc[e] += __shfl_xor(acc[e], off, 64);
  if (lane == 0) {
    float l[8];
#pragma unroll
    for (int e = 0; e < 8; ++e) l[e] = acc[e] + bg[e];
    int i0 = 0;
#pragma unroll
    for (int e = 1; e < 8; ++e) if (l[e] > l[i0]) i0 = e;   // strict > : matches top_k tie rule
    int i1 = (i0 == 0) ? 1 : 0;
#pragma unroll
    for (int e = 0; e < 8; ++e) if (e != i0 && l[e] > l[i1]) i1 = e;
    float ex = expf(l[i1] - l[i0]);
    float s = 1.f + ex;
    gidx[2 * b] = i0; gidx[2 * b + 1] = i1;
    gw[2 * b] = 1.f / s; gw[2 * b + 1] = ex / s;
  }
}

// ---------------- scan: counts -> offsets -> tile table ----------------
__global__ __launch_bounds__(256) void moe_scan(const int* __restrict__ gidx,
                                                int* __restrict__ meta) {
  __shared__ int cnt[8];
  if (threadIdx.x < 8) cnt[threadIdx.x] = 0;
  __syncthreads();
  int loc[8] = {0, 0, 0, 0, 0, 0, 0, 0};
  for (int i = threadIdx.x; i < 8192; i += 256) {
    int e = gidx[i];
#pragma unroll
    for (int q = 0; q < 8; ++q) loc[q] += (e == q) ? 1 : 0;
  }
#pragma unroll
  for (int q = 0; q < 8; ++q) atomicAdd(&cnt[q], loc[q]);
  __syncthreads();
  if (threadIdx.x == 0) {
    int off = 0, t = 0;
    for (int e = 0; e < 8; ++e) {
      int c = cnt[e];
      meta[e] = c;
      meta[8 + e] = off;
      meta[17 + e] = 0;  // fill counters
      int nt = (c + 127) >> 7;
      for (int mt = 0; mt < nt; ++mt) {
        meta[32 + t] = e;
        meta[104 + t] = off + mt * 128;
        meta[176 + t] = off + c;
        ++t;
      }
      off += c;
    }
    meta[16] = off;
    meta[25] = t;
  }
}

// ---------------- scatter assignments into expert-sorted lists ----------------
__global__ __launch_bounds__(256) void moe_scatter(const int* __restrict__ gidx,
    const float* __restrict__ gw, int* __restrict__ meta,
    int* __restrict__ row_index, float* __restrict__ row_w) {
  int i = blockIdx.x * 256 + threadIdx.x;  // 8192 assignments
  int e = gidx[i];
  int pos = meta[8 + e] + atomicAdd(&meta[17 + e], 1);
  row_index[pos] = i >> 1;
  row_w[pos] = gw[i];
}

// ---------------- x fp32 -> bf16 ----------------
__global__ __launch_bounds__(256) void moe_cvtx(const float* __restrict__ x,
                                                uint16_t* __restrict__ xb) {
  size_t i = ((size_t)blockIdx.x * 256 + threadIdx.x) * 4;
  float4 v = *(const float4*)(x + i);
  uint64_t pk = (uint64_t)f2b(v.x) | ((uint64_t)f2b(v.y) << 16) |
                ((uint64_t)f2b(v.z) << 32) | ((uint64_t)f2b(v.w) << 48);
  *(uint64_t*)(xb + i) = pk;
}

// ---------------- W [E][K][N] fp32 -> Wt [E][N][K] bf16 ----------------
__global__ __launch_bounds__(256) void moe_transpose(const float* __restrict__ in,
                                                     uint16_t* __restrict__ outp,
                                                     int K, int N) {
  __shared__ uint16_t t[64][72];
  const int e = blockIdx.z;
  const int k0 = blockIdx.y * 64, n0 = blockIdx.x * 64;
  const int r = threadIdx.x >> 2;          // 0..63
  const int c0 = (threadIdx.x & 3) * 16;   // 0,16,32,48
  const float* src = in + ((size_t)e * K + k0 + r) * N + n0 + c0;
#pragma unroll
  for (int q = 0; q < 4; ++q) {
    float4 v = *(const float4*)(src + q * 4);
    uint64_t pk = (uint64_t)f2b(v.x) | ((uint64_t)f2b(v.y) << 16) |
                  ((uint64_t)f2b(v.z) << 32) | ((uint64_t)f2b(v.w) << 48);
    *(uint64_t*)&t[r][c0 + q * 4] = pk;
  }
  __syncthreads();
  alignas(16) uint16_t buf[16];
#pragma unroll
  for (int j = 0; j < 16; ++j) buf[j] = t[c0 + j][r];
  uint16_t* dst = outp + ((size_t)e * N + n0 + r) * K + k0 + c0;
  *(uint4*)dst = *(const uint4*)&buf[0];
  *(uint4*)(dst + 8) = *(const uint4*)&buf[8];
}

// ---------------- GEMM: 128x128 tile, BK=32, 4 waves, mfma 16x16x32 bf16 ----
// 4 blocks/CU (128KB LDS, 120 regs/wave). Conflict-free LDS swizzle:
// LDS slot (row, ci) holds global k-chunk ci ^ ((row>>1)&3)  =>  a wave's
// b128 frag read (16 rows x same chunk) spans all 32 banks 2-way (free).
// Flat grid + chunked bijective XCD swizzle: consecutive wg (same tile,
// consecutive nb + neighboring tiles) land on one XCD's L2.
// MODE 1: h[pos] = relu(gather(x)[pos] @ W1t[e]^T + b1[e]), ND=4096, KD=1024
// MODE 2: out[rix[pos]] += rw[pos] * (h[pos] @ W2t[e]^T + b2[e]), ND=1024, KD=4096
template <int KD, int ND, int MODE>
__global__ __launch_bounds__(256, 4) void moe_gemm(
    const uint16_t* __restrict__ Am, const uint16_t* __restrict__ Bt,
    const float* __restrict__ bias, const int* __restrict__ meta,
    const int* __restrict__ row_index, const float* __restrict__ row_w,
    uint16_t* __restrict__ hout, float* __restrict__ out) {
  constexpr int NB = ND / 128;
  const int nwg = gridDim.x;
  const int orig = blockIdx.x;
  const int q8 = nwg >> 3, r8 = nwg & 7, xcd = orig & 7, loc = orig >> 3;
  int wg = (xcd < r8 ? xcd * (q8 + 1) : r8 * (q8 + 1) + (xcd - r8) * q8) + loc;
  const int nb = wg % NB;
  const int ty = wg / NB;
  if (ty >= meta[25]) return;
  const int e = meta[32 + ty];
  const int pos0 = meta[104 + ty];
  const int vend = meta[176 + ty];

  __shared__ uint16_t As[2][128 * 32];
  __shared__ uint16_t Bs[2][128 * 32];

  const int tid = threadIdx.x;
  const int lane = tid & 63;
  const int w = tid >> 6;
  const int wr = w >> 1, wc = w & 1;

  // staging sources: chunk c = j*256+tid; LDS slot (row=c>>2, c&3) sources
  // global chunk (c&3)^((row>>1)&3)
  size_t aoff[2], boff[2];
#pragma unroll
  for (int j = 0; j < 2; ++j) {
    int c = j * 256 + tid;
    int row = c >> 2;
    int skc = (c & 3) ^ ((row >> 1) & 3);
    int pos = pos0 + row;
    if (pos > 8191) pos = 8191;
    int ar = (MODE == 1) ? row_index[pos] : pos;
    aoff[j] = ((size_t)ar * KD + (size_t)skc * 8) * 2;
    boff[j] = (((size_t)e * ND + (size_t)nb * 128 + row) * KD + (size_t)skc * 8) * 2;
  }
  const char* Ag = (const char*)Am;
  const char* Bg = (const char*)Bt;

  f32x4_t acc[4][4];
  f32x4_t z;
  z[0] = 0.f; z[1] = 0.f; z[2] = 0.f; z[3] = 0.f;
#pragma unroll
  for (int m = 0; m < 4; ++m)
#pragma unroll
    for (int n = 0; n < 4; ++n) acc[m][n] = z;

  auto stage = [&](int buf, int t) {
#pragma unroll
    for (int j = 0; j < 2; ++j) {
      glds16(Ag + aoff[j] + (size_t)t * 64, &As[buf][(j * 256 + w * 64) * 8]);
      glds16(Bg + boff[j] + (size_t)t * 64, &Bs[buf][(j * 256 + w * 64) * 8]);
    }
  };

  stage(0, 0);
  __syncthreads();
  int cur = 0;
  const int NIT = KD / 32;
  for (int t = 0; t < NIT; ++t) {
    if (t + 1 < NIT) stage(cur ^ 1, t + 1);
    const uint16_t* Ap = As[cur];
    const uint16_t* Bp = Bs[cur];
    bf16x8_t af[4], bfr[4];
#pragma unroll
    for (int m = 0; m < 4; ++m) {
      int row = wr * 64 + m * 16 + (lane & 15);
      int skc = ((lane >> 4) ^ (row >> 1)) & 3;
      af[m] = *(const bf16x8_t*)(Ap + row * 32 + skc * 8);
    }
#pragma unroll
    for (int n = 0; n < 4; ++n) {
      int row = wc * 64 + n * 16 + (lane & 15);
      int skc = ((lane >> 4) ^ (row >> 1)) & 3;
      bfr[n] = *(const bf16x8_t*)(Bp + row * 32 + skc * 8);
    }
#pragma unroll
    for (int m = 0; m < 4; ++m)
#pragma unroll
      for (int n = 0; n < 4; ++n)
        acc[m][n] = __builtin_amdgcn_mfma_f32_16x16x32_bf16(af[m], bfr[n], acc[m][n], 0, 0, 0);
    __syncthreads();  // implicit vmcnt(0)+lgkmcnt(0) drains staged loads
    cur ^= 1;
  }

  // epilogue: C/D mapping col=lane&15, row=(lane>>4)*4+i
  const int cb = nb * 128 + wc * 64;
  if constexpr (MODE == 1) {
#pragma unroll
    for (int m = 0; m < 4; ++m) {
      int pr = pos0 + wr * 64 + m * 16 + ((lane >> 4) << 2);
#pragma unroll
      for (int i = 0; i < 4; ++i) {
        int pos = pr + i;
        if (pos < vend) {
#pragma unroll
          for (int n = 0; n < 4; ++n) {
            int col = cb + n * 16 + (lane & 15);
            float v = acc[m][n][i] + bias[e * ND + col];
            v = fmaxf(v, 0.f);
            hout[(size_t)pos * ND + col] = f2b(v);
          }
        }
      }
    }
  } else {
#pragma unroll
    for (int m = 0; m < 4; ++m) {
      int pr = pos0 + wr * 64 + m * 16 + ((lane >> 4) << 2);
#pragma unroll
      for (int i = 0; i < 4; ++i) {
        int pos = pr + i;
        if (pos < vend) {
          int bi = row_index[pos];
          float wgt = row_w[pos];
          float* orow = out + (size_t)bi * ND;
#pragma unroll
          for (int n = 0; n < 4; ++n) {
            int col = cb + n * 16 + (lane & 15);
            float v = (acc[m][n][i] + bias[e * ND + col]) * wgt;
            atomicAdd(orow + col, v);
          }
        }
      }
    }
  }
}

extern "C" void kernel_launch(void* const* d_in, const int* in_sizes, int n_in,
                              void* d_out, int out_size, void* d_ws, size_t ws_size,
                              hipStream_t stream) {
  const float* x  = (const float*)d_in[0];   // [4096,1024]
  const float* Wg = (const float*)d_in[1];   // [1024,8]
  const float* bg = (const float*)d_in[2];   // [8]
  const float* W1 = (const float*)d_in[3];   // [8,1024,4096]
  const float* b1 = (const float*)d_in[4];   // [8,4096]
  const float* W2 = (const float*)d_in[5];   // [8,4096,1024]
  const float* b2 = (const float*)d_in[6];   // [8,1024]
  float* out = (float*)d_out;                // [4096,1024]

  char* ws = (char*)d_ws;
  uint16_t* w1t = (uint16_t*)ws; ws += (size_t)8 * 4096 * 1024 * 2;  // [E][H][D] bf16
  uint16_t* w2t = (uint16_t*)ws; ws += (size_t)8 * 1024 * 4096 * 2;  // [E][O][H] bf16
  uint16_t* xb  = (uint16_t*)ws; ws += (size_t)4096 * 1024 * 2;      // [B][D] bf16
  uint16_t* h   = (uint16_t*)ws; ws += (size_t)8192 * 4096 * 2;      // [8192][H] bf16
  int*   gidx = (int*)ws;   ws += 8192 * 4;
  float* gw   = (float*)ws; ws += 8192 * 4;
  int*   rix  = (int*)ws;   ws += 8192 * 4;
  float* rw   = (float*)ws; ws += 8192 * 4;
  int*   meta = (int*)ws;   ws += 4096;

  hipMemsetAsync(d_out, 0, (size_t)4096 * 1024 * 4, stream);
  moe_cvtx<<<4096, 256, 0, stream>>>(x, xb);
  moe_transpose<<<dim3(4096 / 64, 1024 / 64, 8), 256, 0, stream>>>(W1, w1t, 1024, 4096);
  moe_transpose<<<dim3(1024 / 64, 4096 / 64, 8), 256, 0, stream>>>(W2, w2t, 4096, 1024);
  moe_gate<<<1024, 256, 0, stream>>>(x, Wg, bg, gidx, gw);
  moe_scan<<<1, 256, 0, stream>>>(gidx, meta);
  moe_scatter<<<32, 256, 0, stream>>>(gidx, gw, meta, rix, rw);
  moe_gemm<1024, 4096, 1><<<dim3(32 * MAXT), 256, 0, stream>>>(xb, w1t, b1, meta, rix, rw, h, nullptr);
  moe_gemm<4096, 1024, 2><<<dim3(8 * MAXT), 256, 0, stream>>>(h, w2t, b2, meta, rix, rw, nullptr, out);
}